// Round 13
// baseline (327.313 us; speedup 1.0000x reference)
//
#include <hip/hip_runtime.h>

#define NT 20        // time steps
#define BT 4096      // batch
#define HD 128       // hidden
#define RT 81920     // total rows = K*B = 20*4096
#define RB 64        // rows per block

typedef _Float16 half8 __attribute__((ext_vector_type(8)));
typedef _Float16 half2v __attribute__((ext_vector_type(2)));
typedef float f32x4 __attribute__((ext_vector_type(4)));
typedef float f32x2 __attribute__((ext_vector_type(2)));
typedef unsigned u32x4 __attribute__((ext_vector_type(4)));

#if defined(__has_builtin)
#  if __has_builtin(__builtin_amdgcn_fdot2)
#    define HAVE_FDOT2 1
#  endif
#endif

__device__ __forceinline__ float clamp01(float x) {
  return fminf(fmaxf(x, 0.0f), 1.0f);
}
__device__ __forceinline__ float htanh(float x) {
  return fminf(fmaxf(x, -1.0f), 1.0f);
}

__device__ __forceinline__ float dot2(half2v a, half2v b, float c) {
#ifdef HAVE_FDOT2
  return __builtin_amdgcn_fdot2(a, b, c, false);
#else
  return fmaf((float)a[0], (float)b[0], fmaf((float)a[1], (float)b[1], c));
#endif
}

// load 8 consecutive f32, scale, convert to f16x8 fragment
__device__ __forceinline__ half8 ldcvt8s(const float* __restrict__ p, float s) {
  f32x4 a = *(const f32x4*)p;
  f32x4 b = *(const f32x4*)(p + 4);
  half8 r;
  r[0] = (_Float16)(a[0] * s); r[1] = (_Float16)(a[1] * s);
  r[2] = (_Float16)(a[2] * s); r[3] = (_Float16)(a[3] * s);
  r[4] = (_Float16)(b[0] * s); r[5] = (_Float16)(b[1] * s);
  r[6] = (_Float16)(b[2] * s); r[7] = (_Float16)(b[3] * s);
  return r;
}
__device__ __forceinline__ half8 ldcvt8(const float* __restrict__ p) {
  return ldcvt8s(p, 1.0f);
}

// LDS-visibility-only barrier (no vmcnt(0) drain; fold stores stay in flight)
__device__ __forceinline__ void lds_barrier() {
  __builtin_amdgcn_sched_barrier(0);
  asm volatile("s_waitcnt lgkmcnt(0)" ::: "memory");
  __builtin_amdgcn_s_barrier();
  __builtin_amdgcn_sched_barrier(0);
}

// Persistent LSTM decoder, 64 rows/block, 8 waves, launch_bounds (512,2).
// R13 single-variable experiment vs R12: pin the 16 W_hh B-fragments (64
// regs) into AGPRs. Occupancy ledger across R1-R12: blocks/CU is set by
// arch+accum <= 128; all (512,2) variants sit at arch 88 + accum ~48 = 136
// -> 1 block/CU (23% occupancy) and a ~7.4k cyc/step barrier convoy with
// nothing to mask it. bW's only consumers are MFMA B-operands, which read
// AGPRs natively on gfx950 -> pinning moves 64 regs to the accum side:
// arch ~40 + accum ~80 = ~120 <= 128 -> 16 waves = 2 blocks/CU.
// Success signals: VGPR_Count drops to ~40-56, Occupancy ~45%.
// Failure signals: FETCH/WRITE spike (pin-induced copies) -> revert.
// Numerics identical to R8/R12 (absmax 3.9e-3).
__global__ __launch_bounds__(512, 2) void decoder_kernel(
    const float* __restrict__ obs, const float* __restrict__ pred,
    const float* __restrict__ Wm1, const float* __restrict__ bm1,
    const float* __restrict__ Wm2, const float* __restrict__ bm2,
    const float* __restrict__ W_ih, const float* __restrict__ W_hh,
    const float* __restrict__ b_ih, const float* __restrict__ b_hh,
    const float* __restrict__ W_out, const float* __restrict__ b_out,
    float* __restrict__ outp)
{
  __shared__ __align__(16) char lds[38400];
  const int tid = threadIdx.x;
  const int w   = tid >> 6;       // wave id 0..7
  const int l   = tid & 63;
  const int l15 = l & 15;
  const int lg  = l >> 4;         // lane group 0..3
  const int wm  = w & 3;          // fold m-tile
  const int wc  = w >> 2;         // fold output column
  const int r0  = blockIdx.x * RB;
  const int b0  = r0 & (BT - 1);

  char* const buf0 = lds;             // h buffer parity 0 (16KB)
  char* const h1l  = lds + 16384;     // parity-1 h buffer; aliases MLP mid acts
  char* const obsl = lds + 32768;     // obs staged: [20][64] packed f16x2 (5KB)
  char* const wol  = lds + 37888;     // W_out f16 [2][128] (512B)

  const f32x4 fzero = {0.f, 0.f, 0.f, 0.f};
  const float SCL = 1.0f / 6.0f;

  const int rdmask = (l15 & 7) << 4;
  const int arow  = l15 * 256;              // A-read row byte
  const int base0 = (16 * lg) ^ rdmask;     // A-read k byte; ao[kt]=(64*kt)^base0
  const int wcol2 = 32 * w + 2 * l15;       // h-write col byte (pre-swizzle)

  // ---- stage W_out (f16), obs (packed f16x2) ----
  if (tid < 256) ((_Float16*)wol)[tid] = (_Float16)W_out[tid];
  for (int i = tid; i < NT * RB; i += 512) {
    int t = i >> 6, row = i & 63;
    int tp = (t > 0) ? t - 1 : 0;
    f32x2 xv = *(const f32x2*)(obs + ((size_t)tp * BT + b0 + row) * 2);
    half2v hp; hp[0] = (_Float16)xv[0]; hp[1] = (_Float16)xv[1];
    *(unsigned*)(obsl + (size_t)i * 4) = __builtin_bit_cast(unsigned, hp);
  }

  // ---------------- Prologue: h0 = MLP(pred) ----------------
  // GEMM1: h1[64x64] = leaky_relu(pred @ Wm1^T + bm1). wave w: m=wm, n=2wc+{0,1}
  {
    half8 a1[4], b1[2][4];
#pragma unroll
    for (int kt = 0; kt < 4; ++kt)
      a1[kt] = ldcvt8(pred + (size_t)(r0 + 16 * wm + l15) * HD + kt * 32 + lg * 8);
#pragma unroll
    for (int j = 0; j < 2; ++j)
#pragma unroll
      for (int kt = 0; kt < 4; ++kt)
        b1[j][kt] = ldcvt8(Wm1 + (l15 + 16 * (2 * wc + j)) * HD + kt * 32 + lg * 8);
    f32x4 acc1[2] = {fzero, fzero};
#pragma unroll
    for (int kt = 0; kt < 4; ++kt)
#pragma unroll
      for (int j = 0; j < 2; ++j)
        acc1[j] = __builtin_amdgcn_mfma_f32_16x16x32_f16(a1[kt], b1[j][kt], acc1[j], 0, 0, 0);
#pragma unroll
    for (int j = 0; j < 2; ++j) {
      int c = l15 + 16 * (2 * wc + j);
      float bb = bm1[c];
#pragma unroll
      for (int reg = 0; reg < 4; ++reg) {
        int row = 16 * wm + 4 * lg + reg;
        float v = acc1[j][reg] + bb;
        v = v >= 0.f ? v : 0.01f * v;
        *(_Float16*)(h1l + row * 128 + ((2 * c) ^ ((row & 7) << 4))) = (_Float16)v;
      }
    }
  }
  __syncthreads();
  // GEMM2: h0[64x128] = h1 @ Wm2^T + bm2 -> buf0. wave w: m=wm, n=4wc+{0..3}
  {
    half8 a2[2], b2[4][2];
#pragma unroll
    for (int kt = 0; kt < 2; ++kt)
      a2[kt] = *(const half8*)(h1l + (16 * wm + l15) * 128 + ((64 * kt + 16 * lg) ^ rdmask));
#pragma unroll
    for (int j = 0; j < 4; ++j)
#pragma unroll
      for (int kt = 0; kt < 2; ++kt)
        b2[j][kt] = ldcvt8(Wm2 + (l15 + 16 * (4 * wc + j)) * 64 + kt * 32 + lg * 8);
    f32x4 acc2[4] = {fzero, fzero, fzero, fzero};
#pragma unroll
    for (int kt = 0; kt < 2; ++kt)
#pragma unroll
      for (int j = 0; j < 4; ++j)
        acc2[j] = __builtin_amdgcn_mfma_f32_16x16x32_f16(a2[kt], b2[j][kt], acc2[j], 0, 0, 0);
#pragma unroll
    for (int j = 0; j < 4; ++j) {
      int c = l15 + 16 * (4 * wc + j);
      float bb = bm2[c];
#pragma unroll
      for (int reg = 0; reg < 4; ++reg) {
        int row = 16 * wm + 4 * lg + reg;
        float v = acc2[j][reg] + bb;
        *(_Float16*)(buf0 + row * 256 + ((2 * c) ^ ((row & 7) << 4))) = (_Float16)v;
      }
    }
  }

  // ---- steady-state per-wave constants ----
  // bW: W_hh fragments, i/f/o rows pre-scaled by 1/6 (hsig prefold) —
  // PINNED TO AGPRs (only consumers are MFMA B-operands; gfx950 reads
  // A/B from AGPRs natively). Aug payload stays arch (feeds cndmask).
  half8 bW[4][4];
  unsigned awp[4], abp[4];
#pragma unroll
  for (int n = 0; n < 4; ++n) {
    const float s = (n == 2) ? 1.0f : SCL;
    int g = 128 * n + 16 * w + l15;
#pragma unroll
    for (int kt = 0; kt < 4; ++kt)
      bW[n][kt] = ldcvt8s(W_hh + (size_t)g * HD + kt * 32 + lg * 8, s);
    half2v t2;
    t2[0] = (_Float16)(W_ih[g * 2 + 0] * s);
    t2[1] = (_Float16)(W_ih[g * 2 + 1] * s);
    awp[n] = __builtin_bit_cast(unsigned, t2);
    float bs = b_ih[g] + b_hh[g];
    half2v t3;
    t3[0] = (_Float16)((n == 2) ? bs : bs * SCL + 0.5f);
    t3[1] = (_Float16)0.0f;
    abp[n] = __builtin_bit_cast(unsigned, t3);
  }
  // AGPR pin: forces the 64 bW regs onto the accumulation side of the
  // unified file, dropping arch demand below the 128-total 2-block boundary.
#pragma unroll
  for (int n = 0; n < 4; ++n)
#pragma unroll
    for (int kt = 0; kt < 4; ++kt)
      asm volatile("" : "+a"(bW[n][kt]));
  const float bo = wc ? b_out[1] : b_out[0];

  // c-state in REGISTERS, indexed by j (compile-time): cst[j] is the cell
  // state of tile mm=(wm+1+j)&3 — the rotation is fixed across steps.
  f32x4 cst[4] = {fzero, fzero, fzero, fzero};

  __syncthreads();  // h0/obs/wol visible; h1l reads done (step0 writes alias)

  // ---------------- 20 recurrent steps ----------------
  for (int t = 0; t < NT; ++t) {
    char* const brd = lds + ((t & 1) << 14);
    char* const bwr = lds + (((t & 1) ^ 1) << 14);

#pragma unroll
    for (int j = 0; j < 4; ++j) {
      const int mm = (wm + 1 + j) & 3;   // fold tile (mm==wm) at j==3

      // A-fragment reads issued up front
      half8 af[5];
#pragma unroll
      for (int kt = 0; kt < 4; ++kt)
        af[kt] = *(const half8*)(brd + mm * 4096 + arow + ((64 * kt) ^ base0));
      {
        unsigned xv = *(const unsigned*)(obsl + ((t << 6) + (mm << 4) + l15) * 4);
        unsigned u0 = (lg == 0) ? xv : 0u;
        unsigned u1 = (lg == 0) ? 0x00003C00u : 0u;  // f16 1.0 in elem 2
        u32x4 xu = {u0, u1, 0u, 0u};
        af[4] = __builtin_bit_cast(half8, xu);
      }

      // MFMA cluster (single acc bank — R8's verified order)
      f32x4 acc[4] = {fzero, fzero, fzero, fzero};
      __builtin_amdgcn_s_setprio(1);
#pragma unroll
      for (int kt = 0; kt < 5; ++kt) {
#pragma unroll
        for (int n = 0; n < 4; ++n) {
          half8 bfrag;
          if (kt < 4) {
            bfrag = bW[n][kt];
          } else {
            unsigned v0 = (lg == 0) ? awp[n] : 0u;
            unsigned v1 = (lg == 0) ? abp[n] : 0u;
            u32x4 bu = {v0, v1, 0u, 0u};
            bfrag = __builtin_bit_cast(half8, bu);
          }
          acc[n] = __builtin_amdgcn_mfma_f32_16x16x32_f16(af[kt], bfrag, acc[n], 0, 0, 0);
        }
      }
      __builtin_amdgcn_s_setprio(0);

      // fold at j==3 (mm==wm): out[t-1] from the already-loaded af —
      // VALU overlapping the MFMA cluster's pipe latency
      if (j == 3 && t > 0) {
        float p = 0.f;
#pragma unroll
        for (int kt = 0; kt < 4; ++kt) {
          const half8 a = af[kt];
          const half8 wf = *(const half8*)(wol + wc * 256 + kt * 64 + lg * 16);
#pragma unroll
          for (int pp = 0; pp < 4; ++pp) {
            half2v ha; ha[0] = a[2 * pp]; ha[1] = a[2 * pp + 1];
            half2v wa; wa[0] = wf[2 * pp]; wa[1] = wf[2 * pp + 1];
            p = dot2(ha, wa, p);
          }
        }
        p += __shfl_xor(p, 16, 64); p += __shfl_xor(p, 32, 64);
        if (l < 16)
          outp[(size_t)(t - 1) * (RT * 2) + (size_t)(r0 + 16 * wm + l) * 2 + wc] = p + bo;
      }

      // fused LSTM update for this tile (lane-local), cst[j] compile-time
      f32x4 cn4;
#pragma unroll
      for (int reg = 0; reg < 4; ++reg) {
        float i_ = clamp01(acc[0][reg]);
        float f_ = clamp01(acc[1][reg]);
        float g_ = htanh(acc[2][reg]);
        float o_ = clamp01(acc[3][reg]);
        float cn = fmaf(f_, cst[j][reg], i_ * g_);
        cn4[reg] = cn;
        float hn = o_ * htanh(cn);
        int rr = 4 * lg + reg;
        int wb = rr * 256 + (wcol2 ^ ((rr & 7) << 4));
        *(_Float16*)(bwr + mm * 4096 + wb) = (_Float16)hn;
      }
      cst[j] = cn4;
    }
    lds_barrier();   // lgkmcnt(0) + s_barrier; fold stores stay in flight
  }

  // ---------------- epilogue: final out from h(20) (buf parity 0) ----------------
  {
    float p = 0.f;
#pragma unroll
    for (int kt = 0; kt < 4; ++kt) {
      half8 a = *(const half8*)(buf0 + wm * 4096 + arow + ((64 * kt) ^ base0));
      const half8 wf = *(const half8*)(wol + wc * 256 + kt * 64 + lg * 16);
#pragma unroll
      for (int pp = 0; pp < 4; ++pp) {
        half2v ha; ha[0] = a[2 * pp]; ha[1] = a[2 * pp + 1];
        half2v wa; wa[0] = wf[2 * pp]; wa[1] = wf[2 * pp + 1];
        p = dot2(ha, wa, p);
      }
    }
    p += __shfl_xor(p, 16, 64); p += __shfl_xor(p, 32, 64);
    if (l < 16)
      outp[(size_t)19 * (RT * 2) + (size_t)(r0 + 16 * wm + l) * 2 + wc] = p + bo;
  }
}

extern "C" void kernel_launch(void* const* d_in, const int* in_sizes, int n_in,
                              void* d_out, int out_size, void* d_ws, size_t ws_size,
                              hipStream_t stream) {
  const float* obs   = (const float*)d_in[0];
  const float* pred  = (const float*)d_in[1];
  const float* Wm1   = (const float*)d_in[2];
  const float* bm1   = (const float*)d_in[3];
  const float* Wm2   = (const float*)d_in[4];
  const float* bm2   = (const float*)d_in[5];
  const float* W_ih  = (const float*)d_in[6];
  const float* W_hh  = (const float*)d_in[7];
  const float* b_ih  = (const float*)d_in[8];
  const float* b_hh  = (const float*)d_in[9];
  const float* W_out = (const float*)d_in[10];
  const float* b_out = (const float*)d_in[11];

  decoder_kernel<<<RT / RB, 512, 0, stream>>>(
      obs, pred, Wm1, bm1, Wm2, bm2, W_ih, W_hh, b_ih, b_hh, W_out, b_out,
      (float*)d_out);
}

// Round 14
// 303.855 us; speedup vs baseline: 1.0772x; 1.0772x over previous
//
#include <hip/hip_runtime.h>

#define NT 20        // time steps
#define BT 4096      // batch
#define HD 128       // hidden
#define RT 81920     // total rows = K*B = 20*4096
#define RB 64        // rows per block

typedef _Float16 half8 __attribute__((ext_vector_type(8)));
typedef _Float16 half2v __attribute__((ext_vector_type(2)));
typedef float f32x4 __attribute__((ext_vector_type(4)));
typedef float f32x2 __attribute__((ext_vector_type(2)));
typedef unsigned u32x4 __attribute__((ext_vector_type(4)));

#if defined(__has_builtin)
#  if __has_builtin(__builtin_amdgcn_fdot2)
#    define HAVE_FDOT2 1
#  endif
#endif

__device__ __forceinline__ float clamp01(float x) {
  return fminf(fmaxf(x, 0.0f), 1.0f);
}
__device__ __forceinline__ float htanh(float x) {
  return fminf(fmaxf(x, -1.0f), 1.0f);
}

__device__ __forceinline__ float dot2(half2v a, half2v b, float c) {
#ifdef HAVE_FDOT2
  return __builtin_amdgcn_fdot2(a, b, c, false);
#else
  return fmaf((float)a[0], (float)b[0], fmaf((float)a[1], (float)b[1], c));
#endif
}

// load 8 consecutive f32, scale, convert to f16x8 fragment
__device__ __forceinline__ half8 ldcvt8s(const float* __restrict__ p, float s) {
  f32x4 a = *(const f32x4*)p;
  f32x4 b = *(const f32x4*)(p + 4);
  half8 r;
  r[0] = (_Float16)(a[0] * s); r[1] = (_Float16)(a[1] * s);
  r[2] = (_Float16)(a[2] * s); r[3] = (_Float16)(a[3] * s);
  r[4] = (_Float16)(b[0] * s); r[5] = (_Float16)(b[1] * s);
  r[6] = (_Float16)(b[2] * s); r[7] = (_Float16)(b[3] * s);
  return r;
}
__device__ __forceinline__ half8 ldcvt8(const float* __restrict__ p) {
  return ldcvt8s(p, 1.0f);
}

// LDS-visibility-only barrier (no vmcnt(0) drain; fold stores stay in flight)
__device__ __forceinline__ void lds_barrier() {
  __builtin_amdgcn_sched_barrier(0);
  asm volatile("s_waitcnt lgkmcnt(0)" ::: "memory");
  __builtin_amdgcn_s_barrier();
  __builtin_amdgcn_sched_barrier(0);
}

// Persistent LSTM decoder, 64 rows/block, 8 waves, launch_bounds (512,2).
// R13 verdict: occupancy is pinned at ~8 waves/CU under (512,2) and is not
// movable by register diets (R11/R12/R13 all neutral). Operating point is
// therefore 2 waves/SIMD with a 256-reg budget of which only ~136 was used.
// R14 SPENDS the headroom on fewer instructions + deeper prefetch:
//  1. bAug[4] hoisted: aug B-fragments are t/j-invariant (-32 cndmask/step)
//  2. wfr[4] hoisted: W_out fold fragments in regs (-4 LDS reads/step)
//  3. wbase[4] hoisted: h-write addresses precomputed (-48 VALU/step)
//  4. A-fragment double-buffer A[2][5]: next j's ds_reads + aug build issue
//     before this j's MFMA cluster -> ds_read latency hidden under MFMA
//     (R7's pattern; R7 failed only because it spilled at the 128-reg cap)
// Est live ~196 <= 256, no spill. Numerics = R8/R12 (absmax 3.9e-3).
// Wave w owns hidden slice [16w,16w+16): gate cols 128n+16w+(l&15) are
// lane-local in the mfma 16x16x32 D-layout (col=l&15, row=4*(l>>4)+reg).
// h: LDS f16 double-buffered, XOR-swizzled byte^=(row&7)<<4. c: registers
// cst[j] <-> tile (wm+1+j)&3 (compile-time index, rotation fixed).
// hsig prefold: i/f/o rows pre-scaled 1/6, bias b/6+0.5 => hsig = clamp01.
__global__ __launch_bounds__(512, 2) void decoder_kernel(
    const float* __restrict__ obs, const float* __restrict__ pred,
    const float* __restrict__ Wm1, const float* __restrict__ bm1,
    const float* __restrict__ Wm2, const float* __restrict__ bm2,
    const float* __restrict__ W_ih, const float* __restrict__ W_hh,
    const float* __restrict__ b_ih, const float* __restrict__ b_hh,
    const float* __restrict__ W_out, const float* __restrict__ b_out,
    float* __restrict__ outp)
{
  __shared__ __align__(16) char lds[38400];
  const int tid = threadIdx.x;
  const int w   = tid >> 6;       // wave id 0..7
  const int l   = tid & 63;
  const int l15 = l & 15;
  const int lg  = l >> 4;         // lane group 0..3
  const int wm  = w & 3;          // fold m-tile
  const int wc  = w >> 2;         // fold output column
  const int r0  = blockIdx.x * RB;
  const int b0  = r0 & (BT - 1);

  char* const buf0 = lds;             // h buffer parity 0 (16KB)
  char* const h1l  = lds + 16384;     // parity-1 h buffer; aliases MLP mid acts
  char* const obsl = lds + 32768;     // obs staged: [20][64] packed f16x2 (5KB)
  char* const wol  = lds + 37888;     // W_out f16 [2][128] (512B)

  const f32x4 fzero = {0.f, 0.f, 0.f, 0.f};
  const float SCL = 1.0f / 6.0f;

  const int rdmask = (l15 & 7) << 4;
  const int arow  = l15 * 256;              // A-read row byte
  const int base0 = (16 * lg) ^ rdmask;     // A-read k byte; ao[kt]=(64*kt)^base0
  const int wcol2 = 32 * w + 2 * l15;       // h-write col byte (pre-swizzle)

  // h-write addresses hoisted (R14.3)
  int wbase[4];
#pragma unroll
  for (int reg = 0; reg < 4; ++reg) {
    int rr = 4 * lg + reg;
    wbase[reg] = rr * 256 + (wcol2 ^ ((rr & 7) << 4));
  }

  // ---- stage W_out (f16), obs (packed f16x2) ----
  if (tid < 256) ((_Float16*)wol)[tid] = (_Float16)W_out[tid];
  for (int i = tid; i < NT * RB; i += 512) {
    int t = i >> 6, row = i & 63;
    int tp = (t > 0) ? t - 1 : 0;
    f32x2 xv = *(const f32x2*)(obs + ((size_t)tp * BT + b0 + row) * 2);
    half2v hp; hp[0] = (_Float16)xv[0]; hp[1] = (_Float16)xv[1];
    *(unsigned*)(obsl + (size_t)i * 4) = __builtin_bit_cast(unsigned, hp);
  }

  // ---------------- Prologue: h0 = MLP(pred) ----------------
  // GEMM1: h1[64x64] = leaky_relu(pred @ Wm1^T + bm1). wave w: m=wm, n=2wc+{0,1}
  {
    half8 a1[4], b1[2][4];
#pragma unroll
    for (int kt = 0; kt < 4; ++kt)
      a1[kt] = ldcvt8(pred + (size_t)(r0 + 16 * wm + l15) * HD + kt * 32 + lg * 8);
#pragma unroll
    for (int j = 0; j < 2; ++j)
#pragma unroll
      for (int kt = 0; kt < 4; ++kt)
        b1[j][kt] = ldcvt8(Wm1 + (l15 + 16 * (2 * wc + j)) * HD + kt * 32 + lg * 8);
    f32x4 acc1[2] = {fzero, fzero};
#pragma unroll
    for (int kt = 0; kt < 4; ++kt)
#pragma unroll
      for (int j = 0; j < 2; ++j)
        acc1[j] = __builtin_amdgcn_mfma_f32_16x16x32_f16(a1[kt], b1[j][kt], acc1[j], 0, 0, 0);
#pragma unroll
    for (int j = 0; j < 2; ++j) {
      int c = l15 + 16 * (2 * wc + j);
      float bb = bm1[c];
#pragma unroll
      for (int reg = 0; reg < 4; ++reg) {
        int row = 16 * wm + 4 * lg + reg;
        float v = acc1[j][reg] + bb;
        v = v >= 0.f ? v : 0.01f * v;
        *(_Float16*)(h1l + row * 128 + ((2 * c) ^ ((row & 7) << 4))) = (_Float16)v;
      }
    }
  }
  __syncthreads();
  // GEMM2: h0[64x128] = h1 @ Wm2^T + bm2 -> buf0. wave w: m=wm, n=4wc+{0..3}
  {
    half8 a2[2], b2[4][2];
#pragma unroll
    for (int kt = 0; kt < 2; ++kt)
      a2[kt] = *(const half8*)(h1l + (16 * wm + l15) * 128 + ((64 * kt + 16 * lg) ^ rdmask));
#pragma unroll
    for (int j = 0; j < 4; ++j)
#pragma unroll
      for (int kt = 0; kt < 2; ++kt)
        b2[j][kt] = ldcvt8(Wm2 + (l15 + 16 * (4 * wc + j)) * 64 + kt * 32 + lg * 8);
    f32x4 acc2[4] = {fzero, fzero, fzero, fzero};
#pragma unroll
    for (int kt = 0; kt < 2; ++kt)
#pragma unroll
      for (int j = 0; j < 4; ++j)
        acc2[j] = __builtin_amdgcn_mfma_f32_16x16x32_f16(a2[kt], b2[j][kt], acc2[j], 0, 0, 0);
#pragma unroll
    for (int j = 0; j < 4; ++j) {
      int c = l15 + 16 * (4 * wc + j);
      float bb = bm2[c];
#pragma unroll
      for (int reg = 0; reg < 4; ++reg) {
        int row = 16 * wm + 4 * lg + reg;
        float v = acc2[j][reg] + bb;
        *(_Float16*)(buf0 + row * 256 + ((2 * c) ^ ((row & 7) << 4))) = (_Float16)v;
      }
    }
  }

  // ---- steady-state per-wave constants ----
  // bW: W_hh fragments (64 regs), i/f/o rows pre-scaled by 1/6 (hsig prefold)
  half8 bW[4][4];
  half8 bAug[4];                    // aug B-fragments, hoisted (R14.1)
#pragma unroll
  for (int n = 0; n < 4; ++n) {
    const float s = (n == 2) ? 1.0f : SCL;
    int g = 128 * n + 16 * w + l15;
#pragma unroll
    for (int kt = 0; kt < 4; ++kt)
      bW[n][kt] = ldcvt8s(W_hh + (size_t)g * HD + kt * 32 + lg * 8, s);
    half2v t2;
    t2[0] = (_Float16)(W_ih[g * 2 + 0] * s);
    t2[1] = (_Float16)(W_ih[g * 2 + 1] * s);
    float bs = b_ih[g] + b_hh[g];
    half2v t3;
    t3[0] = (_Float16)((n == 2) ? bs : bs * SCL + 0.5f);
    t3[1] = (_Float16)0.0f;
    unsigned v0 = (lg == 0) ? __builtin_bit_cast(unsigned, t2) : 0u;
    unsigned v1 = (lg == 0) ? __builtin_bit_cast(unsigned, t3) : 0u;
    u32x4 bu = {v0, v1, 0u, 0u};
    bAug[n] = __builtin_bit_cast(half8, bu);
  }
  const float bo = wc ? b_out[1] : b_out[0];

  // c-state in registers, indexed by j (compile-time; rotation fixed)
  f32x4 cst[4] = {fzero, fzero, fzero, fzero};

  __syncthreads();  // h0/obs/wol visible; h1l reads done (step0 writes alias)

  // W_out fold fragments hoisted into registers (R14.2)
  half8 wfr[4];
#pragma unroll
  for (int kt = 0; kt < 4; ++kt)
    wfr[kt] = *(const half8*)(wol + wc * 256 + kt * 64 + lg * 16);

  // ---------------- 20 recurrent steps ----------------
  for (int t = 0; t < NT; ++t) {
    char* const brd = lds + ((t & 1) << 14);
    char* const bwr = lds + (((t & 1) ^ 1) << 14);

    half8 A[2][5];   // A-fragment double buffer (R14.4); j unrolled -> static idx

    // prefetch j=0 tile (mm = wm+1)
    {
      const int mm0 = (wm + 1) & 3;
#pragma unroll
      for (int kt = 0; kt < 4; ++kt)
        A[0][kt] = *(const half8*)(brd + mm0 * 4096 + arow + ((64 * kt) ^ base0));
      unsigned xv = *(const unsigned*)(obsl + ((t << 6) + (mm0 << 4) + l15) * 4);
      unsigned u0 = (lg == 0) ? xv : 0u;
      unsigned u1 = (lg == 0) ? 0x00003C00u : 0u;  // f16 1.0 in elem 2
      u32x4 xu = {u0, u1, 0u, 0u};
      A[0][4] = __builtin_bit_cast(half8, xu);
    }

#pragma unroll
    for (int j = 0; j < 4; ++j) {
      const int mm = (wm + 1 + j) & 3;   // fold tile (mm==wm) at j==3
      const int cur = j & 1;

      // prefetch NEXT tile's A-fragments before this tile's MFMA cluster
      if (j < 3) {
        const int mn = (wm + 2 + j) & 3;
#pragma unroll
        for (int kt = 0; kt < 4; ++kt)
          A[cur ^ 1][kt] = *(const half8*)(brd + mn * 4096 + arow + ((64 * kt) ^ base0));
        unsigned xv = *(const unsigned*)(obsl + ((t << 6) + (mn << 4) + l15) * 4);
        unsigned u0 = (lg == 0) ? xv : 0u;
        unsigned u1 = (lg == 0) ? 0x00003C00u : 0u;
        u32x4 xu = {u0, u1, 0u, 0u};
        A[cur ^ 1][4] = __builtin_bit_cast(half8, xu);
      }

      // MFMA cluster (single acc bank — R8's verified order)
      f32x4 acc[4] = {fzero, fzero, fzero, fzero};
      __builtin_amdgcn_s_setprio(1);
#pragma unroll
      for (int kt = 0; kt < 5; ++kt) {
#pragma unroll
        for (int n = 0; n < 4; ++n) {
          const half8 bfrag = (kt < 4) ? bW[n][kt] : bAug[n];
          acc[n] = __builtin_amdgcn_mfma_f32_16x16x32_f16(A[cur][kt], bfrag, acc[n], 0, 0, 0);
        }
      }
      __builtin_amdgcn_s_setprio(0);

      // fold at j==3 (mm==wm): out[t-1] from the registered A + wfr —
      // pure-reg VALU overlapping the MFMA cluster's drain
      if (j == 3 && t > 0) {
        float p = 0.f;
#pragma unroll
        for (int kt = 0; kt < 4; ++kt) {
          const half8 a = A[cur][kt];
          const half8 wf = wfr[kt];
#pragma unroll
          for (int pp = 0; pp < 4; ++pp) {
            half2v ha; ha[0] = a[2 * pp]; ha[1] = a[2 * pp + 1];
            half2v wa; wa[0] = wf[2 * pp]; wa[1] = wf[2 * pp + 1];
            p = dot2(ha, wa, p);
          }
        }
        p += __shfl_xor(p, 16, 64); p += __shfl_xor(p, 32, 64);
        if (l < 16)
          outp[(size_t)(t - 1) * (RT * 2) + (size_t)(r0 + 16 * wm + l) * 2 + wc] = p + bo;
      }

      // fused LSTM update for this tile (lane-local), cst[j] compile-time
      f32x4 cn4;
#pragma unroll
      for (int reg = 0; reg < 4; ++reg) {
        float i_ = clamp01(acc[0][reg]);
        float f_ = clamp01(acc[1][reg]);
        float g_ = htanh(acc[2][reg]);
        float o_ = clamp01(acc[3][reg]);
        float cn = fmaf(f_, cst[j][reg], i_ * g_);
        cn4[reg] = cn;
        float hn = o_ * htanh(cn);
        *(_Float16*)(bwr + mm * 4096 + wbase[reg]) = (_Float16)hn;
      }
      cst[j] = cn4;
    }
    lds_barrier();   // lgkmcnt(0) + s_barrier; fold stores stay in flight
  }

  // ---------------- epilogue: final out from h(20) (buf parity 0) ----------------
  {
    float p = 0.f;
#pragma unroll
    for (int kt = 0; kt < 4; ++kt) {
      half8 a = *(const half8*)(buf0 + wm * 4096 + arow + ((64 * kt) ^ base0));
      const half8 wf = wfr[kt];
#pragma unroll
      for (int pp = 0; pp < 4; ++pp) {
        half2v ha; ha[0] = a[2 * pp]; ha[1] = a[2 * pp + 1];
        half2v wa; wa[0] = wf[2 * pp]; wa[1] = wf[2 * pp + 1];
        p = dot2(ha, wa, p);
      }
    }
    p += __shfl_xor(p, 16, 64); p += __shfl_xor(p, 32, 64);
    if (l < 16)
      outp[(size_t)19 * (RT * 2) + (size_t)(r0 + 16 * wm + l) * 2 + wc] = p + bo;
  }
}

extern "C" void kernel_launch(void* const* d_in, const int* in_sizes, int n_in,
                              void* d_out, int out_size, void* d_ws, size_t ws_size,
                              hipStream_t stream) {
  const float* obs   = (const float*)d_in[0];
  const float* pred  = (const float*)d_in[1];
  const float* Wm1   = (const float*)d_in[2];
  const float* bm1   = (const float*)d_in[3];
  const float* Wm2   = (const float*)d_in[4];
  const float* bm2   = (const float*)d_in[5];
  const float* W_ih  = (const float*)d_in[6];
  const float* W_hh  = (const float*)d_in[7];
  const float* b_ih  = (const float*)d_in[8];
  const float* b_hh  = (const float*)d_in[9];
  const float* W_out = (const float*)d_in[10];
  const float* b_out = (const float*)d_in[11];

  decoder_kernel<<<RT / RB, 512, 0, stream>>>(
      obs, pred, Wm1, bm1, Wm2, bm2, W_ih, W_hh, b_ih, b_hh, W_out, b_out,
      (float*)d_out);
}